// Round 7
// baseline (152.639 us; speedup 1.0000x reference)
//
#include <hip/hip_runtime.h>
#include <hip/hip_fp16.h>
#include <math.h>

#define BB 32
#define TT 256
#define DD 1024
#define NNODES 2048
#define EE 65536
#define LN_EPS 1e-5f

typedef _Float16 halfx8 __attribute__((ext_vector_type(8)));
typedef __attribute__((ext_vector_type(4))) float floatx4;

__device__ __forceinline__ float gelu_fast(float x) {
    // tanh-approx gelu: x - x/(1+exp2(x*(2.302118 + 0.102945*x^2)))
    float x2 = x * x;
    float z = x * fmaf(0.10294456f, x2, 2.30211786f);
    float e = __builtin_amdgcn_exp2f(z);
    float r = __builtin_amdgcn_rcpf(1.0f + e);
    return fmaf(-x, r, x);
}

// packed half2 sigmoid-gelu: x / (1 + exp2(-2.4554669 x))
__device__ __forceinline__ __half2 gelu_h2(__half2 x) {
    const __half2 k = __float2half2_rn(-2.4554669f);
    const __half2 one = __float2half2_rn(1.0f);
    __half2 e = h2exp2(__hmul2(x, k));
    return __hmul2(x, h2rcp(__hadd2(e, one)));
}

__device__ __forceinline__ float dot2f(__half2 a, __half2 b, float c) {
#if __has_builtin(__builtin_amdgcn_fdot2)
    typedef _Float16 v2h __attribute__((ext_vector_type(2)));
    return __builtin_amdgcn_fdot2(*(v2h*)&a, *(v2h*)&b, c, false);
#else
    float2 af = __half22float2(a), bf = __half22float2(b);
    return fmaf(af.x, bf.x, fmaf(af.y, bf.y, c));
#endif
}

__device__ __forceinline__ unsigned short f32_to_h16(float f) {
    return __half_as_ushort(__float2half_rn(f));
}

__device__ __forceinline__ void load_lds16(const void* g, void* l) {
    __builtin_amdgcn_global_load_lds(
        (const __attribute__((address_space(1))) void*)g,
        (__attribute__((address_space(3))) void*)l, 16, 0, 0);
}

// ---------------- K1: zero d_out + LayerNorm (blocks 0..31) + prep (32..4127)
__global__ __launch_bounds__(256) void k1_zero_ln_prep_kernel(
    const float* __restrict__ x, const float* __restrict__ g,
    const float* __restrict__ bta, const float* __restrict__ Wf1,
    float* __restrict__ hnorm, float* __restrict__ out,
    unsigned short* __restrict__ nodesH, unsigned short* __restrict__ Wf1T) {
    __shared__ float smem[32 * 33];
    int t = threadIdx.x;
    int b = blockIdx.x;
    if (b < BB) {
        int zi = b * 256 + t;
        if (zi < BB + NNODES * 3) out[zi] = 0.0f;
        float* red = smem;
        const float* row = x + (size_t)b * TT * DD;
        float v[4];
        float s = 0.0f;
        #pragma unroll
        for (int j = 0; j < 4; ++j) { v[j] = row[t + j * 256]; s += v[j]; }
        red[t] = s; __syncthreads();
        for (int off = 128; off > 0; off >>= 1) {
            if (t < off) red[t] += red[t + off];
            __syncthreads();
        }
        float mu = red[0] * (1.0f / DD);
        __syncthreads();
        float sq = 0.0f;
        #pragma unroll
        for (int j = 0; j < 4; ++j) { float d = v[j] - mu; sq += d * d; }
        red[t] = sq; __syncthreads();
        for (int off = 128; off > 0; off >>= 1) {
            if (t < off) red[t] += red[t + off];
            __syncthreads();
        }
        float rstd = rsqrtf(red[0] * (1.0f / DD) + LN_EPS);
        #pragma unroll
        for (int j = 0; j < 4; ++j) {
            int d = t + j * 256;
            hnorm[b * DD + d] = (v[j] - mu) * rstd * g[d] + bta[d];
        }
        return;
    }
    int pb = b - BB;
    if (pb < 2048) {
        int idx4 = (pb * 256 + t) * 4;
        int i = idx4 >> 10;
        int k = idx4 & 1023;
        const float* src = x + ((size_t)(i >> 6) * TT + 1 + (i & 63)) * DD + k;
        float4 v = *(const float4*)src;
        ushort4 o;
        o.x = f32_to_h16(v.x); o.y = f32_to_h16(v.y);
        o.z = f32_to_h16(v.z); o.w = f32_to_h16(v.w);
        *(ushort4*)&nodesH[idx4] = o;
    } else {
        int q = pb - 2048;
        float (*tile)[33] = (float(*)[33])smem;
        int tx = t & 31;
        int ty = t >> 5;
        int n0 = (q & 31) * 32;
        int kg0 = (q >> 5) * 32;
        #pragma unroll
        for (int j = 0; j < 4; ++j) {
            int r = ty * 4 + j;
            tile[r][tx] = Wf1[(size_t)(kg0 + r) * DD + n0 + tx];
        }
        __syncthreads();
        int half = kg0 >> 10;
        int kk0 = kg0 & 1023;
        unsigned short* o = Wf1T + (size_t)half * DD * DD;
        #pragma unroll
        for (int j = 0; j < 4; ++j) {
            int rn = ty * 4 + j;
            o[(size_t)(n0 + rn) * DD + kk0 + tx] = f32_to_h16(tile[tx][rn]);
        }
    }
}

// ---------------- K2: MFMA (f16) pgemm (blocks 0..511, 512 thr = 8 waves,
//                      128i x 64n tiles, 2 blocks/CU, round-3 verified
//                      structure; P stored d-split: [dh][half][2048][512]
//                      so each K3 pass has a 4MB (one-XCD-L2) working set) +
//                      energy1 split-K GEMM (blocks 512..575)
__global__ __launch_bounds__(512) void k2_gemm_kernel(
    const unsigned short* __restrict__ nodesH,
    const unsigned short* __restrict__ Wf1T, const float* __restrict__ bf1,
    unsigned short* __restrict__ P, const float* __restrict__ hnorm,
    const float* __restrict__ We1, float* __restrict__ He) {
    __shared__ unsigned short smem[64 * 64 + 128 * 64];  // 24 KB
    int t = threadIdx.x;
    int b = blockIdx.x;
    if (b < 512) {
        int sb = (b & 7) * 64 + (b >> 3);  // bijective XCD swizzle (512%8==0)
        int half = sb >> 8;
        int n0 = (sb & 15) * 64;
        int i0 = ((sb >> 4) & 15) * 128;
        unsigned short* As = smem;            // [64 n][64 k] swizzled chunks
        unsigned short* Bs = smem + 64 * 64;  // [128 i][64 k]
        int w = t >> 6;
        int lane = t & 63;
        int quad = lane >> 4;
        int l16 = lane & 15;
        int wn = (w & 1) * 32;
        int wi = (w >> 1) * 32;

        const unsigned short* Ag = Wf1T + (size_t)half * DD * DD;
        const unsigned short* Bg = nodesH;

        int sr = lane >> 3;
        int sc = (lane & 7) ^ sr;
        size_t aoff = (size_t)(n0 + w * 8 + sr) * DD + sc * 8;
        size_t boff[2];
        #pragma unroll
        for (int j = 0; j < 2; ++j)
            boff[j] = (size_t)(i0 + w * 16 + j * 8 + sr) * DD + sc * 8;

        floatx4 acc[2][2];
        #pragma unroll
        for (int a = 0; a < 2; ++a)
            #pragma unroll
            for (int c = 0; c < 2; ++c) {
                acc[a][c][0] = 0.f; acc[a][c][1] = 0.f;
                acc[a][c][2] = 0.f; acc[a][c][3] = 0.f;
            }

        for (int k0 = 0; k0 < DD; k0 += 64) {
            load_lds16(Ag + aoff + k0, (void*)(As + (w * 8) * 64));
            #pragma unroll
            for (int j = 0; j < 2; ++j)
                load_lds16(Bg + boff[j] + k0, (void*)(Bs + (w * 16 + j * 8) * 64));
            __syncthreads();
            #pragma unroll
            for (int s = 0; s < 2; ++s) {
                halfx8 af[2], bfr[2];
                #pragma unroll
                for (int f = 0; f < 2; ++f) {
                    int rn = wn + f * 16 + l16;
                    af[f] = *(const halfx8*)&As[rn * 64 + ((((s << 2) | quad) ^ (rn & 7)) << 3)];
                }
                #pragma unroll
                for (int f = 0; f < 2; ++f) {
                    int ri = wi + f * 16 + l16;
                    bfr[f] = *(const halfx8*)&Bs[ri * 64 + ((((s << 2) | quad) ^ (ri & 7)) << 3)];
                }
                #pragma unroll
                for (int fa = 0; fa < 2; ++fa)
                    #pragma unroll
                    for (int fb = 0; fb < 2; ++fb)
                        acc[fa][fb] = __builtin_amdgcn_mfma_f32_16x16x32_f16(
                            af[fa], bfr[fb], acc[fa][fb], 0, 0, 0);
            }
            __syncthreads();
        }

        // P layout: [dh][half][2048][512], dh = n>>9 (4-col group never
        // straddles the 512 boundary since n is 4-aligned within 64-tiles)
        #pragma unroll
        for (int fa = 0; fa < 2; ++fa) {
            int n = n0 + wn + fa * 16 + quad * 4;
            float4 badd = make_float4(0.f, 0.f, 0.f, 0.f);
            if (half == 0) badd = *(const float4*)(bf1 + n);
            size_t dh = n >> 9;
            size_t col = n & 511;
            unsigned short* Pout = P + ((dh * 2 + half) * NNODES) * 512;
            #pragma unroll
            for (int fb = 0; fb < 2; ++fb) {
                int i = i0 + wi + fb * 16 + l16;
                floatx4 v = acc[fa][fb];
                ushort4 o;
                o.x = f32_to_h16(v[0] + badd.x);
                o.y = f32_to_h16(v[1] + badd.y);
                o.z = f32_to_h16(v[2] + badd.z);
                o.w = f32_to_h16(v[3] + badd.w);
                *(ushort4*)&Pout[(size_t)i * 512 + col] = o;
            }
        }
        return;
    }
    // energy1: He[ks][r0+r][col] = sum_{64k chunk} h[r][k]*We1[k][col]
    {
        int q = b - 512;
        float* hs = (float*)smem;  // [k][r] 64x16
        int col = (q & 1) * 512 + t;
        int k0 = ((q >> 1) & 15) * 64;
        int r0 = (q >> 5) * 16;
        for (int idx = t; idx < 64 * 16; idx += 512) {
            int r = idx & 15, k = idx >> 4;
            hs[idx] = hnorm[(size_t)(r0 + r) * DD + k0 + k];
        }
        __syncthreads();
        float acc[16];
        #pragma unroll
        for (int r = 0; r < 16; ++r) acc[r] = 0.0f;
        #pragma unroll 4
        for (int k = 0; k < 64; ++k) {
            float wv = We1[(size_t)(k0 + k) * DD + col];
            const float* hrow = hs + k * 16;
            #pragma unroll
            for (int j = 0; j < 4; ++j) {
                float4 h4 = *(const float4*)(hrow + j * 4);
                acc[j * 4 + 0] = fmaf(h4.x, wv, acc[j * 4 + 0]);
                acc[j * 4 + 1] = fmaf(h4.y, wv, acc[j * 4 + 1]);
                acc[j * 4 + 2] = fmaf(h4.z, wv, acc[j * 4 + 2]);
                acc[j * 4 + 3] = fmaf(h4.w, wv, acc[j * 4 + 3]);
            }
        }
        float* o = He + (size_t)((q >> 1) & 15) * 32 * DD;
        #pragma unroll
        for (int r = 0; r < 16; ++r) o[(size_t)(r0 + r) * DD + col] = acc[r];
    }
}

// ---------------- K3 pass (dh=0,1): edge kernel over one 512-dim half.
// 2 edges per wave (32768 waves/pass, 8192 blocks): all FOUR row gathers
// (both edges x both endpoints) issue back-to-back before any compute —
// max memory-level parallelism, ~35% shorter per-wave serial chain than the
// 4-edge rotation, 2x the wave-level parallelism to hide what remains.
// dh=0 writes per-edge partial dot to fmpart; dh=1 adds partial + bias and
// does the force atomics. Blocks 8192..8223 (pass 0 only): energy2.
__global__ __launch_bounds__(256) void k3_edge_pass_kernel(
    const unsigned short* __restrict__ P, const int* __restrict__ edge_index,
    const float* __restrict__ evec, const float* __restrict__ edist,
    const float* __restrict__ Wf2, const float* __restrict__ bf2,
    const float* __restrict__ He, const float* __restrict__ be1,
    const float* __restrict__ We2, const float* __restrict__ be2,
    float* __restrict__ fmpart, float* __restrict__ out, int dh) {
    __shared__ float red[256];
    int t = threadIdx.x;
    int b = blockIdx.x;
    if (b < 8192) {
        float* forces = out + BB;
        int lane = t & 63;
        int wv = b * 4 + (t >> 6);  // 0..32767
        int dbase = lane * 8;       // 8 f16 = 16B per lane, 64 lanes = full row
        // Wf2 lane slice for this d-half: 4 half2
        __half2 wh[4];
        {
            float4 a = *(const float4*)(Wf2 + dh * 512 + dbase);
            float4 c = *(const float4*)(Wf2 + dh * 512 + dbase + 4);
            wh[0] = __floats2half2_rn(a.x, a.y);
            wh[1] = __floats2half2_rn(a.z, a.w);
            wh[2] = __floats2half2_rn(c.x, c.y);
            wh[3] = __floats2half2_rn(c.z, c.w);
        }
        float bias2 = bf2[0];
        const unsigned short* P0h = P + (size_t)(dh * 2 + 0) * NNODES * 512;
        const unsigned short* P1h = P + (size_t)(dh * 2 + 1) * NNODES * 512;

        int e0 = wv, e1 = wv + 32768;
        int i00 = __builtin_amdgcn_readfirstlane(edge_index[e0]);
        int i01 = __builtin_amdgcn_readfirstlane(edge_index[EE + e0]);
        int i10 = __builtin_amdgcn_readfirstlane(edge_index[e1]);
        int i11 = __builtin_amdgcn_readfirstlane(edge_index[EE + e1]);

        // all four gathers in flight before any compute
        float4 r00 = *(const float4*)(P0h + (size_t)i00 * 512 + dbase);
        float4 r01 = *(const float4*)(P1h + (size_t)i01 * 512 + dbase);
        float4 r10 = *(const float4*)(P0h + (size_t)i10 * 512 + dbase);
        float4 r11 = *(const float4*)(P1h + (size_t)i11 * 512 + dbase);

        float acc0 = 0.0f, acc1 = 0.0f;
        {
            const __half2* h0 = (const __half2*)&r00;
            const __half2* h1 = (const __half2*)&r01;
            #pragma unroll
            for (int jj = 0; jj < 4; ++jj) {
                __half2 hv = __hadd2(h0[jj], h1[jj]);
                acc0 = dot2f(gelu_h2(hv), wh[jj], acc0);
            }
        }
        {
            const __half2* h0 = (const __half2*)&r10;
            const __half2* h1 = (const __half2*)&r11;
            #pragma unroll
            for (int jj = 0; jj < 4; ++jj) {
                __half2 hv = __hadd2(h0[jj], h1[jj]);
                acc1 = dot2f(gelu_h2(hv), wh[jj], acc1);
            }
        }
        // packed 2-edge reduce: lane<32 finishes e0, lane>=32 finishes e1
        acc0 += __shfl_xor(acc0, 32, 64);
        acc1 += __shfl_xor(acc1, 32, 64);
        float r = (lane < 32) ? acc0 : acc1;
        #pragma unroll
        for (int off = 16; off > 0; off >>= 1) r += __shfl_xor(r, off, 64);
        int e = (lane < 32) ? e0 : e1;
        if (dh == 0) {
            if ((lane & 31) == 0) fmpart[e] = r;
        } else {
            float fm = r + fmpart[e] + bias2;
            int l5 = lane & 31;
            if (l5 < 3) {
                int i0 = (lane < 32) ? i00 : i10;
                float sc = fm / edist[e];
                atomicAdd(&forces[i0 * 3 + l5], sc * evec[e * 3 + l5]);
            }
        }
        return;
    }
    // energy2 (pass dh==0 only, blocks 8192..8223): sum 16 partials, gelu,
    // dot We2 (fp32 path)
    {
        int bb = b - 8192;
        float p = 0.0f;
        #pragma unroll
        for (int j = 0; j < 4; ++j) {
            int c = t * 4 + j;
            float s = 0.0f;
            #pragma unroll
            for (int ks = 0; ks < 16; ++ks)
                s += He[(size_t)ks * 32 * DD + bb * DD + c];
            s += be1[c];
            p += gelu_fast(s) * We2[c];
        }
        red[t] = p; __syncthreads();
        for (int off = 128; off > 0; off >>= 1) {
            if (t < off) red[t] += red[t + off];
            __syncthreads();
        }
        if (t == 0) out[bb] = red[0] + be2[0];
    }
}

extern "C" void kernel_launch(void* const* d_in, const int* in_sizes, int n_in,
                              void* d_out, int out_size, void* d_ws, size_t ws_size,
                              hipStream_t stream) {
    const float* x    = (const float*)d_in[0];
    const int* edge_index = (const int*)d_in[2];
    const float* evec = (const float*)d_in[3];
    const float* edist = (const float*)d_in[4];
    const float* ln_g = (const float*)d_in[6];
    const float* ln_b = (const float*)d_in[7];
    const float* We1  = (const float*)d_in[8];
    const float* be1  = (const float*)d_in[9];
    const float* We2  = (const float*)d_in[10];
    const float* be2  = (const float*)d_in[11];
    const float* Wf1  = (const float*)d_in[12];
    const float* bf1  = (const float*)d_in[13];
    const float* Wf2  = (const float*)d_in[14];
    const float* bf2  = (const float*)d_in[15];

    float* out = (float*)d_out;  // [0:32] energy, [32:32+6144] forces

    // ws layout:
    // [0, 8MB)          : P fp16 [2 dh][2 half][2048][512]
    // [8MB, 10MB+128KB) : hnorm (128 KB) + He (2 MB)
    // [11MB, 15MB)      : nodesH fp16 [2048][1024]
    // [16MB, 20MB)      : Wf1T  fp16 [2][1024][1024]
    // [21MB, 21MB+256KB): fmpart f32 [65536]
    char* wsb = (char*)d_ws;
    unsigned short* P      = (unsigned short*)(wsb);
    float* hnorm           = (float*)(wsb + (8u << 20));
    float* He              = (float*)(wsb + (8u << 20) + (128u << 10));
    unsigned short* nodesH = (unsigned short*)(wsb + (11u << 20));
    unsigned short* Wf1T   = (unsigned short*)(wsb + (16u << 20));
    float* fmpart          = (float*)(wsb + (21u << 20));

    k1_zero_ln_prep_kernel<<<4128, 256, 0, stream>>>(x, ln_g, ln_b, Wf1, hnorm,
                                                     out, nodesH, Wf1T);
    k2_gemm_kernel<<<576, 512, 0, stream>>>(nodesH, Wf1T, bf1, P, hnorm, We1, He);
    k3_edge_pass_kernel<<<8224, 256, 0, stream>>>(P, edge_index, evec, edist,
                                                  Wf2, bf2, He, be1, We2, be2,
                                                  fmpart, out, 0);
    k3_edge_pass_kernel<<<8192, 256, 0, stream>>>(P, edge_index, evec, edist,
                                                  Wf2, bf2, He, be1, We2, be2,
                                                  fmpart, out, 1);
}

// Round 8
// 148.632 us; speedup vs baseline: 1.0270x; 1.0270x over previous
//
#include <hip/hip_runtime.h>
#include <hip/hip_fp16.h>
#include <math.h>

#define BB 32
#define TT 256
#define DD 1024
#define NNODES 2048
#define EE 65536
#define LN_EPS 1e-5f

typedef _Float16 halfx8 __attribute__((ext_vector_type(8)));
typedef __attribute__((ext_vector_type(4))) float floatx4;

__device__ __forceinline__ float gelu_fast(float x) {
    // tanh-approx gelu: x - x/(1+exp2(x*(2.302118 + 0.102945*x^2)))
    float x2 = x * x;
    float z = x * fmaf(0.10294456f, x2, 2.30211786f);
    float e = __builtin_amdgcn_exp2f(z);
    float r = __builtin_amdgcn_rcpf(1.0f + e);
    return fmaf(-x, r, x);
}

// packed half2 sigmoid-gelu: x / (1 + exp2(-2.4554669 x))
__device__ __forceinline__ __half2 gelu_h2(__half2 x) {
    const __half2 k = __float2half2_rn(-2.4554669f);
    const __half2 one = __float2half2_rn(1.0f);
    __half2 e = h2exp2(__hmul2(x, k));
    return __hmul2(x, h2rcp(__hadd2(e, one)));
}

__device__ __forceinline__ float dot2f(__half2 a, __half2 b, float c) {
#if __has_builtin(__builtin_amdgcn_fdot2)
    typedef _Float16 v2h __attribute__((ext_vector_type(2)));
    return __builtin_amdgcn_fdot2(*(v2h*)&a, *(v2h*)&b, c, false);
#else
    float2 af = __half22float2(a), bf = __half22float2(b);
    return fmaf(af.x, bf.x, fmaf(af.y, bf.y, c));
#endif
}

__device__ __forceinline__ unsigned short f32_to_h16(float f) {
    return __half_as_ushort(__float2half_rn(f));
}

__device__ __forceinline__ void load_lds16(const void* g, void* l) {
    __builtin_amdgcn_global_load_lds(
        (const __attribute__((address_space(1))) void*)g,
        (__attribute__((address_space(3))) void*)l, 16, 0, 0);
}

// ---------------- K1: zero d_out + LayerNorm (blocks 0..31) + prep (32..4127)
__global__ __launch_bounds__(256) void k1_zero_ln_prep_kernel(
    const float* __restrict__ x, const float* __restrict__ g,
    const float* __restrict__ bta, const float* __restrict__ Wf1,
    float* __restrict__ hnorm, float* __restrict__ out,
    unsigned short* __restrict__ nodesH, unsigned short* __restrict__ Wf1T) {
    __shared__ float smem[32 * 33];
    int t = threadIdx.x;
    int b = blockIdx.x;
    if (b < BB) {
        int zi = b * 256 + t;
        if (zi < BB + NNODES * 3) out[zi] = 0.0f;
        float* red = smem;
        const float* row = x + (size_t)b * TT * DD;
        float v[4];
        float s = 0.0f;
        #pragma unroll
        for (int j = 0; j < 4; ++j) { v[j] = row[t + j * 256]; s += v[j]; }
        red[t] = s; __syncthreads();
        for (int off = 128; off > 0; off >>= 1) {
            if (t < off) red[t] += red[t + off];
            __syncthreads();
        }
        float mu = red[0] * (1.0f / DD);
        __syncthreads();
        float sq = 0.0f;
        #pragma unroll
        for (int j = 0; j < 4; ++j) { float d = v[j] - mu; sq += d * d; }
        red[t] = sq; __syncthreads();
        for (int off = 128; off > 0; off >>= 1) {
            if (t < off) red[t] += red[t + off];
            __syncthreads();
        }
        float rstd = rsqrtf(red[0] * (1.0f / DD) + LN_EPS);
        #pragma unroll
        for (int j = 0; j < 4; ++j) {
            int d = t + j * 256;
            hnorm[b * DD + d] = (v[j] - mu) * rstd * g[d] + bta[d];
        }
        return;
    }
    int pb = b - BB;
    if (pb < 2048) {
        int idx4 = (pb * 256 + t) * 4;
        int i = idx4 >> 10;
        int k = idx4 & 1023;
        const float* src = x + ((size_t)(i >> 6) * TT + 1 + (i & 63)) * DD + k;
        float4 v = *(const float4*)src;
        ushort4 o;
        o.x = f32_to_h16(v.x); o.y = f32_to_h16(v.y);
        o.z = f32_to_h16(v.z); o.w = f32_to_h16(v.w);
        *(ushort4*)&nodesH[idx4] = o;
    } else {
        int q = pb - 2048;
        float (*tile)[33] = (float(*)[33])smem;
        int tx = t & 31;
        int ty = t >> 5;
        int n0 = (q & 31) * 32;
        int kg0 = (q >> 5) * 32;
        #pragma unroll
        for (int j = 0; j < 4; ++j) {
            int r = ty * 4 + j;
            tile[r][tx] = Wf1[(size_t)(kg0 + r) * DD + n0 + tx];
        }
        __syncthreads();
        int half = kg0 >> 10;
        int kk0 = kg0 & 1023;
        unsigned short* o = Wf1T + (size_t)half * DD * DD;
        #pragma unroll
        for (int j = 0; j < 4; ++j) {
            int rn = ty * 4 + j;
            o[(size_t)(n0 + rn) * DD + kk0 + tx] = f32_to_h16(tile[tx][rn]);
        }
    }
}

// ---------------- K2: MFMA (f16) pgemm (blocks 0..511, 512 thr = 8 waves,
//                      128i x 64n tiles, 2 blocks/CU, round-3 verified
//                      structure; P stored d-split: [dh][half][2048][512]) +
//                      energy1 split-K GEMM (blocks 512..575)
__global__ __launch_bounds__(512) void k2_gemm_kernel(
    const unsigned short* __restrict__ nodesH,
    const unsigned short* __restrict__ Wf1T, const float* __restrict__ bf1,
    unsigned short* __restrict__ P, const float* __restrict__ hnorm,
    const float* __restrict__ We1, float* __restrict__ He) {
    __shared__ unsigned short smem[64 * 64 + 128 * 64];  // 24 KB
    int t = threadIdx.x;
    int b = blockIdx.x;
    if (b < 512) {
        int sb = (b & 7) * 64 + (b >> 3);  // bijective XCD swizzle (512%8==0)
        int half = sb >> 8;
        int n0 = (sb & 15) * 64;
        int i0 = ((sb >> 4) & 15) * 128;
        unsigned short* As = smem;            // [64 n][64 k] swizzled chunks
        unsigned short* Bs = smem + 64 * 64;  // [128 i][64 k]
        int w = t >> 6;
        int lane = t & 63;
        int quad = lane >> 4;
        int l16 = lane & 15;
        int wn = (w & 1) * 32;
        int wi = (w >> 1) * 32;

        const unsigned short* Ag = Wf1T + (size_t)half * DD * DD;
        const unsigned short* Bg = nodesH;

        int sr = lane >> 3;
        int sc = (lane & 7) ^ sr;
        size_t aoff = (size_t)(n0 + w * 8 + sr) * DD + sc * 8;
        size_t boff[2];
        #pragma unroll
        for (int j = 0; j < 2; ++j)
            boff[j] = (size_t)(i0 + w * 16 + j * 8 + sr) * DD + sc * 8;

        floatx4 acc[2][2];
        #pragma unroll
        for (int a = 0; a < 2; ++a)
            #pragma unroll
            for (int c = 0; c < 2; ++c) {
                acc[a][c][0] = 0.f; acc[a][c][1] = 0.f;
                acc[a][c][2] = 0.f; acc[a][c][3] = 0.f;
            }

        for (int k0 = 0; k0 < DD; k0 += 64) {
            load_lds16(Ag + aoff + k0, (void*)(As + (w * 8) * 64));
            #pragma unroll
            for (int j = 0; j < 2; ++j)
                load_lds16(Bg + boff[j] + k0, (void*)(Bs + (w * 16 + j * 8) * 64));
            __syncthreads();
            #pragma unroll
            for (int s = 0; s < 2; ++s) {
                halfx8 af[2], bfr[2];
                #pragma unroll
                for (int f = 0; f < 2; ++f) {
                    int rn = wn + f * 16 + l16;
                    af[f] = *(const halfx8*)&As[rn * 64 + ((((s << 2) | quad) ^ (rn & 7)) << 3)];
                }
                #pragma unroll
                for (int f = 0; f < 2; ++f) {
                    int ri = wi + f * 16 + l16;
                    bfr[f] = *(const halfx8*)&Bs[ri * 64 + ((((s << 2) | quad) ^ (ri & 7)) << 3)];
                }
                #pragma unroll
                for (int fa = 0; fa < 2; ++fa)
                    #pragma unroll
                    for (int fb = 0; fb < 2; ++fb)
                        acc[fa][fb] = __builtin_amdgcn_mfma_f32_16x16x32_f16(
                            af[fa], bfr[fb], acc[fa][fb], 0, 0, 0);
            }
            __syncthreads();
        }

        // P layout: [dh][half][2048][512], dh = n>>9 (4-col group never
        // straddles the 512 boundary since n is 4-aligned within 64-tiles)
        #pragma unroll
        for (int fa = 0; fa < 2; ++fa) {
            int n = n0 + wn + fa * 16 + quad * 4;
            float4 badd = make_float4(0.f, 0.f, 0.f, 0.f);
            if (half == 0) badd = *(const float4*)(bf1 + n);
            size_t dh = n >> 9;
            size_t col = n & 511;
            unsigned short* Pout = P + ((dh * 2 + half) * NNODES) * 512;
            #pragma unroll
            for (int fb = 0; fb < 2; ++fb) {
                int i = i0 + wi + fb * 16 + l16;
                floatx4 v = acc[fa][fb];
                ushort4 o;
                o.x = f32_to_h16(v[0] + badd.x);
                o.y = f32_to_h16(v[1] + badd.y);
                o.z = f32_to_h16(v[2] + badd.z);
                o.w = f32_to_h16(v[3] + badd.w);
                *(ushort4*)&Pout[(size_t)i * 512 + col] = o;
            }
        }
        return;
    }
    // energy1: He[ks][r0+r][col] = sum_{64k chunk} h[r][k]*We1[k][col]
    {
        int q = b - 512;
        float* hs = (float*)smem;  // [k][r] 64x16
        int col = (q & 1) * 512 + t;
        int k0 = ((q >> 1) & 15) * 64;
        int r0 = (q >> 5) * 16;
        for (int idx = t; idx < 64 * 16; idx += 512) {
            int r = idx & 15, k = idx >> 4;
            hs[idx] = hnorm[(size_t)(r0 + r) * DD + k0 + k];
        }
        __syncthreads();
        float acc[16];
        #pragma unroll
        for (int r = 0; r < 16; ++r) acc[r] = 0.0f;
        #pragma unroll 4
        for (int k = 0; k < 64; ++k) {
            float wv = We1[(size_t)(k0 + k) * DD + col];
            const float* hrow = hs + k * 16;
            #pragma unroll
            for (int j = 0; j < 4; ++j) {
                float4 h4 = *(const float4*)(hrow + j * 4);
                acc[j * 4 + 0] = fmaf(h4.x, wv, acc[j * 4 + 0]);
                acc[j * 4 + 1] = fmaf(h4.y, wv, acc[j * 4 + 1]);
                acc[j * 4 + 2] = fmaf(h4.z, wv, acc[j * 4 + 2]);
                acc[j * 4 + 3] = fmaf(h4.w, wv, acc[j * 4 + 3]);
            }
        }
        float* o = He + (size_t)((q >> 1) & 15) * 32 * DD;
        #pragma unroll
        for (int r = 0; r < 16; ++r) o[(size_t)(r0 + r) * DD + col] = acc[r];
    }
}

// ---------------- K3 (single launch): energy2 (blocks 0..31) + edge halves
// (blocks 32..8223). Force is LINEAR in fm, so each 512-dim half contributes
// (partial + bias/2) * evec/dist directly via atomics — no fmpart buffer, no
// second launch, no inter-pass grid drain. Block bb=b-32: dh=bb>>12 selects
// the d-half (4MB P slab), eb=bb&4095 the edge group; 4 edges/wave with
// one-edge-ahead register double buffer (R6-verified structure).
__global__ __launch_bounds__(256) void k3_edge_energy2_kernel(
    const unsigned short* __restrict__ P, const int* __restrict__ edge_index,
    const float* __restrict__ evec, const float* __restrict__ edist,
    const float* __restrict__ Wf2, const float* __restrict__ bf2,
    const float* __restrict__ He, const float* __restrict__ be1,
    const float* __restrict__ We2, const float* __restrict__ be2,
    float* __restrict__ out) {
    __shared__ float red[256];
    int t = threadIdx.x;
    int b = blockIdx.x;
    if (b >= 32) {
        int bb = b - 32;
        int dh = bb >> 12;   // 0: blocks 32..4127, 1: blocks 4128..8223
        int eb = bb & 4095;
        float* forces = out + BB;
        int lane = t & 63;
        int wv = eb * 4 + (t >> 6);  // 0..16383
        int dbase = lane * 8;        // 8 f16 = 16B/lane, 64 lanes = full row
        // Wf2 lane slice for this d-half: 4 half2
        __half2 wh[4];
        {
            float4 a = *(const float4*)(Wf2 + dh * 512 + dbase);
            float4 c = *(const float4*)(Wf2 + dh * 512 + dbase + 4);
            wh[0] = __floats2half2_rn(a.x, a.y);
            wh[1] = __floats2half2_rn(a.z, a.w);
            wh[2] = __floats2half2_rn(c.x, c.y);
            wh[3] = __floats2half2_rn(c.z, c.w);
        }
        float hbias = 0.5f * bf2[0];  // bias split evenly across the 2 halves
        const unsigned short* P0h = P + (size_t)(dh * 2 + 0) * NNODES * 512;
        const unsigned short* P1h = P + (size_t)(dh * 2 + 1) * NNODES * 512;

        int i0v[4], i1v[4];
        #pragma unroll
        for (int j = 0; j < 4; ++j) {
            int e = wv + j * 16384;
            i0v[j] = __builtin_amdgcn_readfirstlane(edge_index[e]);
            i1v[j] = __builtin_amdgcn_readfirstlane(edge_index[EE + e]);
        }

        // stage buffers: [buf][0] = p0 slice, [buf][1] = p1 slice (16B each)
        float4 buf[2][2];
        buf[0][0] = *(const float4*)(P0h + (size_t)i0v[0] * 512 + dbase);
        buf[0][1] = *(const float4*)(P1h + (size_t)i1v[0] * 512 + dbase);
        float accs[2];
        #pragma unroll
        for (int j = 0; j < 4; ++j) {
            if (j < 3) {
                buf[(j + 1) & 1][0] = *(const float4*)(P0h + (size_t)i0v[j + 1] * 512 + dbase);
                buf[(j + 1) & 1][1] = *(const float4*)(P1h + (size_t)i1v[j + 1] * 512 + dbase);
            }
            const float4* cb = buf[j & 1];
            float acc = 0.0f;
            {
                const __half2* h0 = (const __half2*)&cb[0];
                const __half2* h1 = (const __half2*)&cb[1];
                #pragma unroll
                for (int jj = 0; jj < 4; ++jj) {
                    __half2 hv = __hadd2(h0[jj], h1[jj]);
                    acc = dot2f(gelu_h2(hv), wh[jj], acc);
                }
            }
            accs[j & 1] = acc;
            if (j & 1) {
                float a0 = accs[0], a1 = accs[1];
                a0 += __shfl_xor(a0, 32, 64);
                a1 += __shfl_xor(a1, 32, 64);
                float r = (lane < 32) ? a0 : a1;
                #pragma unroll
                for (int off = 16; off > 0; off >>= 1) r += __shfl_xor(r, off, 64);
                float fm = r + hbias;  // this half's share of fm
                int l5 = lane & 31;
                if (l5 < 3) {
                    int je = (lane < 32) ? (j - 1) : j;
                    int e = wv + je * 16384;
                    int i0 = (lane < 32) ? i0v[j - 1] : i0v[j];
                    float sc = fm / edist[e];
                    atomicAdd(&forces[i0 * 3 + l5], sc * evec[e * 3 + l5]);
                }
            }
        }
        return;
    }
    // energy2 (blocks 0..31, scheduled first): sum 16 partials, gelu,
    // dot We2 (fp32 path)
    {
        int bb = b;
        float p = 0.0f;
        #pragma unroll
        for (int j = 0; j < 4; ++j) {
            int c = t * 4 + j;
            float s = 0.0f;
            #pragma unroll
            for (int ks = 0; ks < 16; ++ks)
                s += He[(size_t)ks * 32 * DD + bb * DD + c];
            s += be1[c];
            p += gelu_fast(s) * We2[c];
        }
        red[t] = p; __syncthreads();
        for (int off = 128; off > 0; off >>= 1) {
            if (t < off) red[t] += red[t + off];
            __syncthreads();
        }
        if (t == 0) out[bb] = red[0] + be2[0];
    }
}

extern "C" void kernel_launch(void* const* d_in, const int* in_sizes, int n_in,
                              void* d_out, int out_size, void* d_ws, size_t ws_size,
                              hipStream_t stream) {
    const float* x    = (const float*)d_in[0];
    const int* edge_index = (const int*)d_in[2];
    const float* evec = (const float*)d_in[3];
    const float* edist = (const float*)d_in[4];
    const float* ln_g = (const float*)d_in[6];
    const float* ln_b = (const float*)d_in[7];
    const float* We1  = (const float*)d_in[8];
    const float* be1  = (const float*)d_in[9];
    const float* We2  = (const float*)d_in[10];
    const float* be2  = (const float*)d_in[11];
    const float* Wf1  = (const float*)d_in[12];
    const float* bf1  = (const float*)d_in[13];
    const float* Wf2  = (const float*)d_in[14];
    const float* bf2  = (const float*)d_in[15];

    float* out = (float*)d_out;  // [0:32] energy, [32:32+6144] forces

    // ws layout:
    // [0, 8MB)          : P fp16 [2 dh][2 half][2048][512]
    // [8MB, 10MB+128KB) : hnorm (128 KB) + He (2 MB)
    // [11MB, 15MB)      : nodesH fp16 [2048][1024]
    // [16MB, 20MB)      : Wf1T  fp16 [2][1024][1024]
    char* wsb = (char*)d_ws;
    unsigned short* P      = (unsigned short*)(wsb);
    float* hnorm           = (float*)(wsb + (8u << 20));
    float* He              = (float*)(wsb + (8u << 20) + (128u << 10));
    unsigned short* nodesH = (unsigned short*)(wsb + (11u << 20));
    unsigned short* Wf1T   = (unsigned short*)(wsb + (16u << 20));

    k1_zero_ln_prep_kernel<<<4128, 256, 0, stream>>>(x, ln_g, ln_b, Wf1, hnorm,
                                                     out, nodesH, Wf1T);
    k2_gemm_kernel<<<576, 512, 0, stream>>>(nodesH, Wf1T, bf1, P, hnorm, We1, He);
    k3_edge_energy2_kernel<<<8224, 256, 0, stream>>>(P, edge_index, evec, edist,
                                                     Wf2, bf2, He, be1, We2, be2,
                                                     out);
}